// Round 2
// baseline (1753.376 us; speedup 1.0000x reference)
//
#include <hip/hip_runtime.h>
#include <hip/hip_bf16.h>
#include <math.h>

#define ALPHA 0.1f
#define K_ITERS 10

// ---------------- CSR build ----------------

__global__ __launch_bounds__(256) void k_count(const int* __restrict__ ei, int E,
                                               int* __restrict__ cnt) {
    int stride = gridDim.x * blockDim.x;
    for (int e = blockIdx.x * blockDim.x + threadIdx.x; e < E; e += stride) {
        atomicAdd(&cnt[ei[E + e]], 1);   // dst row
    }
}

__global__ __launch_bounds__(256) void k_dinv(const int* __restrict__ cnt,
                                              float* __restrict__ dinv, int N) {
    int i = blockIdx.x * blockDim.x + threadIdx.x;
    if (i < N) dinv[i] = rsqrtf((float)(cnt[i] + 1));   // +1 self loop, never 0
}

__global__ __launch_bounds__(1024) void k_scan(const int* __restrict__ cnt,
                                               int* __restrict__ row_ptr, int N) {
    __shared__ int sums[1024];
    int t = threadIdx.x;
    int chunk = (N + 1023) >> 10;
    int start = t * chunk;
    int end = min(start + chunk, N);
    if (start > N) start = N;
    int s = 0;
    for (int i = start; i < end; ++i) s += cnt[i];
    sums[t] = s;
    __syncthreads();
    // Hillis-Steele inclusive scan over 1024 partials
    for (int ofs = 1; ofs < 1024; ofs <<= 1) {
        int v = (t >= ofs) ? sums[t - ofs] : 0;
        __syncthreads();
        sums[t] += v;
        __syncthreads();
    }
    int run = (t == 0) ? 0 : sums[t - 1];   // exclusive base for this chunk
    for (int i = start; i < end; ++i) { row_ptr[i] = run; run += cnt[i]; }
    if (t == 1023) row_ptr[N] = run;        // == E
}

__global__ __launch_bounds__(256) void k_fill(const int* __restrict__ ei, int E,
                                              const int* __restrict__ row_ptr,
                                              const float* __restrict__ dinv,
                                              int* __restrict__ fill,
                                              int2* __restrict__ packed) {
    int stride = gridDim.x * blockDim.x;
    for (int e = blockIdx.x * blockDim.x + threadIdx.x; e < E; e += stride) {
        int s = ei[e];
        int d = ei[E + e];
        int pos = atomicAdd(&fill[d], 1);
        packed[row_ptr[d] + pos] = make_int2(s, __float_as_int(dinv[s]));
    }
}

// ---------------- fused MLP: h0 = relu(x@W1+b1)@W2+b2 ----------------
// 32-node tile per block, 256 threads. One 32x257 LDS buffer reused
// (x-tile for phase 1, hid-tile for phase 2). Stride 257 pad kills
// phase same-bank reads across rows.

__global__ __launch_bounds__(256) void k_mlp(const float* __restrict__ x,
                                             const float* __restrict__ W1,
                                             const float* __restrict__ b1,
                                             const float* __restrict__ W2,
                                             const float* __restrict__ b2,
                                             float* __restrict__ h0,
                                             float* __restrict__ hA, int N) {
    __shared__ float tile[32 * 257];
    int t = threadIdx.x;
    int base = blockIdx.x * 32;

    // stage x tile (32 x 256 fp32), float4 per thread x8, coalesced
    for (int j = 0; j < 8; ++j) {
        int flat = j * 1024 + t * 4;       // float index within tile
        int r = flat >> 8, c = flat & 255;
        int row = base + r;
        float4 v = make_float4(0.f, 0.f, 0.f, 0.f);
        if (row < N) v = *(const float4*)(x + (size_t)row * 256 + c);
        *(float4*)&tile[r * 257 + c] = v;
    }
    __syncthreads();

    // phase 1: hid = relu(x@W1+b1), thread owns 4 rows x 8 cols
    int rg = t >> 5;          // 0..7  -> rows rg*4 .. rg*4+3
    int cg = t & 31;          // 0..31 -> cols cg*8 .. cg*8+7
    float acc[4][8];
    #pragma unroll
    for (int i = 0; i < 4; ++i)
        #pragma unroll
        for (int j = 0; j < 8; ++j) acc[i][j] = 0.f;

    #pragma unroll 2
    for (int k = 0; k < 256; ++k) {
        const float4 w0 = *(const float4*)(W1 + (size_t)k * 256 + cg * 8);
        const float4 w1 = *(const float4*)(W1 + (size_t)k * 256 + cg * 8 + 4);
        float wv[8] = {w0.x, w0.y, w0.z, w0.w, w1.x, w1.y, w1.z, w1.w};
        float xv[4];
        #pragma unroll
        for (int i = 0; i < 4; ++i) xv[i] = tile[(rg * 4 + i) * 257 + k];
        #pragma unroll
        for (int i = 0; i < 4; ++i)
            #pragma unroll
            for (int j = 0; j < 8; ++j) acc[i][j] += xv[i] * wv[j];
    }

    const float4 ba = *(const float4*)(b1 + cg * 8);
    const float4 bb = *(const float4*)(b1 + cg * 8 + 4);
    float bv[8] = {ba.x, ba.y, ba.z, ba.w, bb.x, bb.y, bb.z, bb.w};

    __syncthreads();   // all x-tile reads done before overwrite
    #pragma unroll
    for (int i = 0; i < 4; ++i) {
        int r = rg * 4 + i;
        #pragma unroll
        for (int j = 0; j < 8; ++j)
            tile[r * 257 + cg * 8 + j] = fmaxf(acc[i][j] + bv[j], 0.f);
    }
    __syncthreads();

    // phase 2: h0 = hid@W2+b2, thread owns 1 row x 8 cols
    int r2 = t >> 3;           // 0..31
    int cb = (t & 7) * 8;      // 0..56
    float acc2[8] = {0.f, 0.f, 0.f, 0.f, 0.f, 0.f, 0.f, 0.f};
    #pragma unroll 4
    for (int k = 0; k < 256; ++k) {
        float hv = tile[r2 * 257 + k];
        const float4 w0 = *(const float4*)(W2 + (size_t)k * 64 + cb);
        const float4 w1 = *(const float4*)(W2 + (size_t)k * 64 + cb + 4);
        acc2[0] += hv * w0.x; acc2[1] += hv * w0.y;
        acc2[2] += hv * w0.z; acc2[3] += hv * w0.w;
        acc2[4] += hv * w1.x; acc2[5] += hv * w1.y;
        acc2[6] += hv * w1.z; acc2[7] += hv * w1.w;
    }
    int row = base + r2;
    if (row < N) {
        const float4 c0 = *(const float4*)(b2 + cb);
        const float4 c1 = *(const float4*)(b2 + cb + 4);
        float4 o0 = make_float4(acc2[0] + c0.x, acc2[1] + c0.y,
                                acc2[2] + c0.z, acc2[3] + c0.w);
        float4 o1 = make_float4(acc2[4] + c1.x, acc2[5] + c1.y,
                                acc2[6] + c1.z, acc2[7] + c1.w);
        *(float4*)(h0 + (size_t)row * 64 + cb)     = o0;
        *(float4*)(h0 + (size_t)row * 64 + cb + 4) = o1;
        *(float4*)(hA + (size_t)row * 64 + cb)     = o0;   // h starts at h0
        *(float4*)(hA + (size_t)row * 64 + cb + 4) = o1;
    }
}

// ---------------- propagation: one wave per row, lane = column ----------------
// agg[i] = dinv[i] * ( sum_{e: dst=i} dinv[src]*h[src] + dinv[i]*h[i] )
// h_new  = 0.9*agg + 0.1*h0 ; last iter fuses log_softmax and writes d_out.

__global__ __launch_bounds__(256) void k_prop(const float* __restrict__ h_in,
                                              float* __restrict__ h_out,
                                              const float* __restrict__ h0,
                                              const int* __restrict__ row_ptr,
                                              const int2* __restrict__ packed,
                                              const float* __restrict__ dinv,
                                              int N, int last,
                                              float* __restrict__ out) {
    int wid = threadIdx.x >> 6;
    int lane = threadIdx.x & 63;
    int row = blockIdx.x * 4 + wid;
    if (row >= N) return;

    float dv = dinv[row];
    int p = row_ptr[row];
    int pe = row_ptr[row + 1];
    float acc = dv * h_in[(size_t)row * 64 + lane];   // self loop term

    for (; p + 1 < pe; p += 2) {
        int2 a = packed[p];
        int2 b = packed[p + 1];
        float ha = h_in[(size_t)a.x * 64 + lane];
        float hb = h_in[(size_t)b.x * 64 + lane];
        acc += __int_as_float(a.y) * ha;
        acc += __int_as_float(b.y) * hb;
    }
    if (p < pe) {
        int2 a = packed[p];
        acc += __int_as_float(a.y) * h_in[(size_t)a.x * 64 + lane];
    }

    float v = (1.0f - ALPHA) * (dv * acc) + ALPHA * h0[(size_t)row * 64 + lane];

    if (!last) {
        h_out[(size_t)row * 64 + lane] = v;
    } else {
        float m = v;
        #pragma unroll
        for (int o = 32; o; o >>= 1) m = fmaxf(m, __shfl_xor(m, o));
        float e = __expf(v - m);
        float ssum = e;
        #pragma unroll
        for (int o = 32; o; o >>= 1) ssum += __shfl_xor(ssum, o);
        out[(size_t)row * 64 + lane] = v - m - logf(ssum);
    }
}

// ---------------- launch ----------------

extern "C" void kernel_launch(void* const* d_in, const int* in_sizes, int n_in,
                              void* d_out, int out_size, void* d_ws, size_t ws_size,
                              hipStream_t stream) {
    const float* x  = (const float*)d_in[0];
    const int*   ei = (const int*)d_in[1];
    const float* W1 = (const float*)d_in[2];
    const float* b1 = (const float*)d_in[3];
    const float* W2 = (const float*)d_in[4];
    const float* b2 = (const float*)d_in[5];
    float* out = (float*)d_out;

    int N = in_sizes[0] / 256;
    int E = in_sizes[1] / 2;

    // workspace carve-up (256B aligned)
    char* ws = (char*)d_ws;
    size_t off = 0;
    auto carve = [&](size_t bytes) -> void* {
        void* p = ws + off;
        off += (bytes + 255) & ~(size_t)255;
        return p;
    };
    int*   cnt     = (int*)carve((size_t)N * 4);
    int*   fillc   = (int*)carve((size_t)N * 4);
    int*   row_ptr = (int*)carve((size_t)(N + 1) * 4);
    float* dinv    = (float*)carve((size_t)N * 4);
    int2*  packed  = (int2*)carve((size_t)E * 8);
    float* h0      = (float*)carve((size_t)N * 64 * 4);
    float* hB      = (float*)carve((size_t)N * 64 * 4);
    // hA aliased onto d_out: with even K_ITERS, hA is read at iters 0,2,..,8
    // and dead by the last iter, which writes the final result into `out`.
    float* hA      = out;

    hipMemsetAsync(cnt, 0, (size_t)N * 4, stream);
    hipMemsetAsync(fillc, 0, (size_t)N * 4, stream);

    k_count<<<2048, 256, 0, stream>>>(ei, E, cnt);
    k_dinv<<<(N + 255) / 256, 256, 0, stream>>>(cnt, dinv, N);
    k_scan<<<1, 1024, 0, stream>>>(cnt, row_ptr, N);
    k_fill<<<2048, 256, 0, stream>>>(ei, E, row_ptr, dinv, fillc, packed);

    k_mlp<<<(N + 31) / 32, 256, 0, stream>>>(x, W1, b1, W2, b2, h0, hA, N);

    const float* hin = hA;
    float* hout = hB;
    for (int it = 0; it < K_ITERS; ++it) {
        int last = (it == K_ITERS - 1) ? 1 : 0;
        k_prop<<<(N + 3) / 4, 256, 0, stream>>>(hin, hout, h0, row_ptr, packed,
                                                dinv, N, last, out);
        const float* tmp = hin;
        hin = hout;
        hout = (float*)tmp;
    }
}

// Round 6
// 965.095 us; speedup vs baseline: 1.8168x; 1.8168x over previous
//
#include <hip/hip_runtime.h>
#include <hip/hip_bf16.h>
#include <math.h>

#define ALPHA 0.1f
#define K_ITERS 10

typedef __attribute__((ext_vector_type(8))) short short8;
typedef __attribute__((ext_vector_type(4))) float floatx4;

static __device__ __forceinline__ float bf2f(unsigned short u) {
    union { unsigned int i; float f; } v;
    v.i = ((unsigned int)u) << 16;
    return v.f;
}
static __device__ __forceinline__ unsigned short f2bf(float f) {
    union { float f; unsigned int i; } v;
    v.f = f;
    unsigned int r = v.i + 0x7FFF + ((v.i >> 16) & 1);   // round-nearest-even
    return (unsigned short)(r >> 16);
}

// ---------------- CSR build ----------------

__global__ __launch_bounds__(256) void k_count(const int* __restrict__ ei, int E,
                                               int* __restrict__ cnt) {
    int stride = gridDim.x * blockDim.x;
    for (int e = blockIdx.x * blockDim.x + threadIdx.x; e < E; e += stride)
        atomicAdd(&cnt[ei[E + e]], 1);   // dst row
}

__global__ __launch_bounds__(256) void k_dinv(const int* __restrict__ cnt,
                                              float* __restrict__ dinv, int N) {
    int i = blockIdx.x * blockDim.x + threadIdx.x;
    if (i < N) dinv[i] = rsqrtf((float)(cnt[i] + 1));   // +1 self loop
}

__global__ __launch_bounds__(1024) void k_scan(const int* __restrict__ cnt,
                                               int* __restrict__ row_ptr, int N) {
    __shared__ int sums[1024];
    int t = threadIdx.x;
    int chunk = (N + 1023) >> 10;
    int start = t * chunk;
    int end = min(start + chunk, N);
    if (start > N) start = N;
    int s = 0;
    for (int i = start; i < end; ++i) s += cnt[i];
    sums[t] = s;
    __syncthreads();
    for (int ofs = 1; ofs < 1024; ofs <<= 1) {
        int v = (t >= ofs) ? sums[t - ofs] : 0;
        __syncthreads();
        sums[t] += v;
        __syncthreads();
    }
    int run = (t == 0) ? 0 : sums[t - 1];
    for (int i = start; i < end; ++i) { row_ptr[i] = run; run += cnt[i]; }
    if (t == 1023) row_ptr[N] = run;
}

__global__ __launch_bounds__(256) void k_fill(const int* __restrict__ ei, int E,
                                              const int* __restrict__ row_ptr,
                                              const float* __restrict__ dinv,
                                              int* __restrict__ fill,
                                              int2* __restrict__ packed) {
    int stride = gridDim.x * blockDim.x;
    for (int e = blockIdx.x * blockDim.x + threadIdx.x; e < E; e += stride) {
        int s = ei[e];
        int d = ei[E + e];
        int pos = atomicAdd(&fill[d], 1);
        packed[row_ptr[d] + pos] = make_int2(s, __float_as_int(dinv[s]));
    }
}

// ---------------- weight convert: W1t[n][k], W2t[n][k] in bf16 ----------------

__global__ __launch_bounds__(256) void k_convert(const float* __restrict__ W1,
                                                 const float* __restrict__ W2,
                                                 unsigned short* __restrict__ W1t,
                                                 unsigned short* __restrict__ W2t) {
    int idx = blockIdx.x * 256 + threadIdx.x;
    if (idx < 65536) {                       // W1: [k=256][n=256] -> W1t[n][k]
        int k = idx >> 8, n = idx & 255;
        W1t[n * 256 + k] = f2bf(W1[idx]);
    }
    int i2 = idx - 65536;
    if (i2 >= 0 && i2 < 16384) {             // W2: [k=256][n=64] -> W2t[n][k]
        int k = i2 >> 6, n = i2 & 63;
        W2t[n * 256 + k] = f2bf(W2[i2]);
    }
}

// ---------------- MFMA MLP: h0 = relu(x@W1+b1)@W2+b2 (bf16 in, fp32 acc) -----
// Block = 256 thr = 4 waves, 64 node-rows per block.
// Phase 1: H[64][256] = relu(X@W1+b1); wave w owns hidden cols [64w,64w+64).
// Phase 2: OUT[64][64] = H@W2+b2;      wave w owns rows [16w,16w+16).
// X/H share one 32 KB LDS tile, XOR-swizzled (eidx ^= (row&7)<<3) so the
// stride-512B ds_read_b128 column reads spread across 8 bank groups.
// mfma_f32_16x16x32_bf16: A/B frag = 8 contiguous k at k=8*(l>>4), row/col=l&15
// (k-map errors cancel A-vs-B); C/D: col=lane&15, row=(lane>>4)*4+reg (verified).

__global__ __launch_bounds__(256) void k_mlp(const float* __restrict__ x,
                                             const unsigned short* __restrict__ W1t,
                                             const float* __restrict__ b1,
                                             const unsigned short* __restrict__ W2t,
                                             const float* __restrict__ b2,
                                             unsigned short* __restrict__ h0b,
                                             unsigned short* __restrict__ hAb,
                                             int N) {
    __shared__ unsigned short xs[64 * 256];
    int t = threadIdx.x;
    int base = blockIdx.x * 64;
    int w  = t >> 6;          // wave 0..3
    int l  = t & 63;
    int lr = l & 15;          // row-in-tile (A) / col-in-tile (B,D)
    int lk = l >> 4;          // k-group 0..3

    // ---- stage x tile (64 x 256 fp32 -> bf16), swizzled ----
    #pragma unroll
    for (int pass = 0; pass < 16; ++pass) {
        int f = pass * 256 + t;            // float4 id 0..4095
        int r = f >> 6;
        int c4 = (f & 63) << 2;
        float4 v = make_float4(0.f, 0.f, 0.f, 0.f);
        int row = base + r;
        if (row < N) v = *(const float4*)(x + (size_t)row * 256 + c4);
        int e = (r * 256 + c4) ^ ((r & 7) << 3);
        ushort4 pk;
        pk.x = f2bf(v.x); pk.y = f2bf(v.y); pk.z = f2bf(v.z); pk.w = f2bf(v.w);
        *(ushort4*)&xs[e] = pk;
    }
    __syncthreads();

    // ---- phase 1 ----
    floatx4 acc[4][4];
    #pragma unroll
    for (int mt = 0; mt < 4; ++mt)
        #pragma unroll
        for (int nt = 0; nt < 4; ++nt)
            acc[mt][nt] = (floatx4){0.f, 0.f, 0.f, 0.f};

    #pragma unroll
    for (int kc = 0; kc < 8; ++kc) {
        short8 af[4], bf[4];
        #pragma unroll
        for (int mt = 0; mt < 4; ++mt) {
            int m = mt * 16 + lr;
            int e = (m * 256 + kc * 32 + lk * 8) ^ ((m & 7) << 3);
            af[mt] = *(const short8*)&xs[e];
        }
        #pragma unroll
        for (int nt = 0; nt < 4; ++nt) {
            int n = w * 64 + nt * 16 + lr;
            bf[nt] = *(const short8*)&W1t[n * 256 + kc * 32 + lk * 8];
        }
        #pragma unroll
        for (int mt = 0; mt < 4; ++mt)
            #pragma unroll
            for (int nt = 0; nt < 4; ++nt)
                acc[mt][nt] = __builtin_amdgcn_mfma_f32_16x16x32_bf16(
                    af[mt], bf[nt], acc[mt][nt], 0, 0, 0);
    }

    float b1v[4];
    #pragma unroll
    for (int nt = 0; nt < 4; ++nt) b1v[nt] = b1[w * 64 + nt * 16 + lr];

    __syncthreads();   // everyone done reading x tile
    #pragma unroll
    for (int mt = 0; mt < 4; ++mt)
        #pragma unroll
        for (int nt = 0; nt < 4; ++nt)
            #pragma unroll
            for (int r = 0; r < 4; ++r) {
                int m = mt * 16 + lk * 4 + r;           // D row map
                int n = w * 64 + nt * 16 + lr;          // D col map
                float hv = fmaxf(acc[mt][nt][r] + b1v[nt], 0.f);
                xs[(m * 256 + n) ^ ((m & 7) << 3)] = f2bf(hv);
            }
    __syncthreads();

    // ---- phase 2 ----
    floatx4 acc2[4];
    #pragma unroll
    for (int nt = 0; nt < 4; ++nt) acc2[nt] = (floatx4){0.f, 0.f, 0.f, 0.f};

    #pragma unroll
    for (int kc = 0; kc < 8; ++kc) {
        int m = w * 16 + lr;
        int e = (m * 256 + kc * 32 + lk * 8) ^ ((m & 7) << 3);
        short8 af = *(const short8*)&xs[e];
        #pragma unroll
        for (int nt = 0; nt < 4; ++nt) {
            int n = nt * 16 + lr;
            short8 bf_ = *(const short8*)&W2t[n * 256 + kc * 32 + lk * 8];
            acc2[nt] = __builtin_amdgcn_mfma_f32_16x16x32_bf16(
                af, bf_, acc2[nt], 0, 0, 0);
        }
    }

    float b2v[4];
    #pragma unroll
    for (int nt = 0; nt < 4; ++nt) b2v[nt] = b2[nt * 16 + lr];

    #pragma unroll
    for (int nt = 0; nt < 4; ++nt)
        #pragma unroll
        for (int r = 0; r < 4; ++r) {
            int rg = base + w * 16 + lk * 4 + r;
            if (rg < N) {
                int col = nt * 16 + lr;
                unsigned short bv = f2bf(acc2[nt][r] + b2v[nt]);
                h0b[(size_t)rg * 64 + col] = bv;
                hAb[(size_t)rg * 64 + col] = bv;
            }
        }
}

// ---------------- propagation (bf16 h, fp32 accum) ----------------
// One wave per row, lane = column. Edge descriptors for the row are loaded
// once lane-parallel and broadcast via __shfl -> 8-deep independent gathers.

__global__ __launch_bounds__(256) void k_prop(const unsigned short* __restrict__ h_in,
                                              unsigned short* __restrict__ h_out,
                                              const unsigned short* __restrict__ h0,
                                              const int* __restrict__ row_ptr,
                                              const int2* __restrict__ packed,
                                              const float* __restrict__ dinv,
                                              int N, int last,
                                              float* __restrict__ out) {
    int wid = threadIdx.x >> 6;
    int lane = threadIdx.x & 63;
    int row = blockIdx.x * 4 + wid;
    if (row >= N) return;

    float dv = dinv[row];
    int p = row_ptr[row];
    int deg = row_ptr[row + 1] - p;
    float acc = dv * bf2f(h_in[(size_t)row * 64 + lane]);   // self loop

    for (int b = 0; b < deg; b += 64) {
        int m = min(64, deg - b);
        int2 d = make_int2(0, 0);
        if (lane < m) d = packed[p + b + lane];
        int j = 0;
        for (; j + 8 <= m; j += 8) {
            float partial = 0.f;
            #pragma unroll
            for (int u = 0; u < 8; ++u) {
                int s = __shfl(d.x, j + u);
                float wgt = __int_as_float(__shfl(d.y, j + u));
                partial += wgt * bf2f(h_in[(size_t)s * 64 + lane]);
            }
            acc += partial;
        }
        for (; j < m; ++j) {
            int s = __shfl(d.x, j);
            float wgt = __int_as_float(__shfl(d.y, j));
            acc += wgt * bf2f(h_in[(size_t)s * 64 + lane]);
        }
    }

    float v = (1.0f - ALPHA) * (dv * acc) + ALPHA * bf2f(h0[(size_t)row * 64 + lane]);

    if (!last) {
        h_out[(size_t)row * 64 + lane] = f2bf(v);
    } else {
        float mx = v;
        #pragma unroll
        for (int o = 32; o; o >>= 1) mx = fmaxf(mx, __shfl_xor(mx, o));
        float e = __expf(v - mx);
        float ssum = e;
        #pragma unroll
        for (int o = 32; o; o >>= 1) ssum += __shfl_xor(ssum, o);
        out[(size_t)row * 64 + lane] = v - mx - logf(ssum);
    }
}

// ---------------- launch ----------------

extern "C" void kernel_launch(void* const* d_in, const int* in_sizes, int n_in,
                              void* d_out, int out_size, void* d_ws, size_t ws_size,
                              hipStream_t stream) {
    const float* x  = (const float*)d_in[0];
    const int*   ei = (const int*)d_in[1];
    const float* W1 = (const float*)d_in[2];
    const float* b1 = (const float*)d_in[3];
    const float* W2 = (const float*)d_in[4];
    const float* b2 = (const float*)d_in[5];
    float* out = (float*)d_out;

    int N = in_sizes[0] / 256;
    int E = in_sizes[1] / 2;

    char* ws = (char*)d_ws;
    size_t off = 0;
    auto carve = [&](size_t bytes) -> void* {
        void* p = ws + off;
        off += (bytes + 255) & ~(size_t)255;
        return p;
    };
    int*            cnt     = (int*)carve((size_t)N * 4);
    int*            fillc   = (int*)carve((size_t)N * 4);
    int*            row_ptr = (int*)carve((size_t)(N + 1) * 4);
    float*          dinv    = (float*)carve((size_t)N * 4);
    int2*           packed  = (int2*)carve((size_t)E * 8);
    unsigned short* W1t     = (unsigned short*)carve(256 * 256 * 2);
    unsigned short* W2t     = (unsigned short*)carve(64 * 256 * 2);
    unsigned short* h0b     = (unsigned short*)carve((size_t)N * 64 * 2);
    unsigned short* hAb     = (unsigned short*)carve((size_t)N * 64 * 2);
    unsigned short* hBb     = (unsigned short*)carve((size_t)N * 64 * 2);

    hipMemsetAsync(cnt, 0, (size_t)N * 4, stream);
    hipMemsetAsync(fillc, 0, (size_t)N * 4, stream);

    k_count<<<2048, 256, 0, stream>>>(ei, E, cnt);
    k_dinv<<<(N + 255) / 256, 256, 0, stream>>>(cnt, dinv, N);
    k_scan<<<1, 1024, 0, stream>>>(cnt, row_ptr, N);
    k_fill<<<2048, 256, 0, stream>>>(ei, E, row_ptr, dinv, fillc, packed);
    k_convert<<<320, 256, 0, stream>>>(W1, W2, W1t, W2t);

    k_mlp<<<(N + 63) / 64, 256, 0, stream>>>(x, W1t, b1, W2t, b2, h0b, hAb, N);

    const unsigned short* hin = hAb;
    unsigned short* hout = hBb;
    for (int it = 0; it < K_ITERS; ++it) {
        int last = (it == K_ITERS - 1) ? 1 : 0;
        k_prop<<<(N + 3) / 4, 256, 0, stream>>>(hin, hout, h0b, row_ptr, packed,
                                                dinv, N, last, out);
        const unsigned short* tmp = hin;
        hin = hout;
        hout = (unsigned short*)tmp;
    }
}

// Round 7
// 762.885 us; speedup vs baseline: 2.2983x; 1.2651x over previous
//
#include <hip/hip_runtime.h>
#include <hip/hip_bf16.h>
#include <math.h>

#define ALPHA 0.1f
#define K_ITERS 10

typedef __attribute__((ext_vector_type(8))) short short8;
typedef __attribute__((ext_vector_type(4))) float floatx4;

static __device__ __forceinline__ float bf2f(unsigned short u) {
    union { unsigned int i; float f; } v;
    v.i = ((unsigned int)u) << 16;
    return v.f;
}
static __device__ __forceinline__ unsigned short f2bf(float f) {
    union { float f; unsigned int i; } v;
    v.f = f;
    unsigned int r = v.i + 0x7FFF + ((v.i >> 16) & 1);   // round-nearest-even
    return (unsigned short)(r >> 16);
}

// ---------------- CSR build ----------------

__global__ __launch_bounds__(256) void k_count(const int* __restrict__ ei, int E,
                                               int* __restrict__ cnt) {
    int stride = gridDim.x * blockDim.x;
    for (int e = blockIdx.x * blockDim.x + threadIdx.x; e < E; e += stride)
        atomicAdd(&cnt[ei[E + e]], 1);   // dst row
}

__global__ __launch_bounds__(256) void k_dinv(const int* __restrict__ cnt,
                                              float* __restrict__ dinv, int N) {
    int i = blockIdx.x * blockDim.x + threadIdx.x;
    if (i < N) dinv[i] = rsqrtf((float)(cnt[i] + 1));   // +1 self loop
}

// ---- parallel exclusive scan of cnt -> row_ptr (3 phases, 1024 elems/block) ----

__global__ __launch_bounds__(256) void k_scan_part(const int* __restrict__ cnt,
                                                   int* __restrict__ partial, int N) {
    __shared__ int red[256];
    int t = threadIdx.x;
    int base = blockIdx.x * 1024 + t * 4;
    int s = 0;
    #pragma unroll
    for (int u = 0; u < 4; ++u) { int i = base + u; if (i < N) s += cnt[i]; }
    red[t] = s;
    __syncthreads();
    for (int o = 128; o; o >>= 1) {
        if (t < o) red[t] += red[t + o];
        __syncthreads();
    }
    if (t == 0) partial[blockIdx.x] = red[0];
}

__global__ __launch_bounds__(128) void k_scan_off(const int* __restrict__ partial,
                                                  int* __restrict__ blkoff,
                                                  int* __restrict__ row_ptr_last,
                                                  int nblk) {
    __shared__ int sc[128];
    int t = threadIdx.x;
    sc[t] = (t < nblk) ? partial[t] : 0;
    __syncthreads();
    for (int o = 1; o < 128; o <<= 1) {
        int w = (t >= o) ? sc[t - o] : 0;
        __syncthreads();
        sc[t] += w;
        __syncthreads();
    }
    if (t < nblk) blkoff[t] = t ? sc[t - 1] : 0;
    if (t == 127) *row_ptr_last = sc[127];   // == E
}

__global__ __launch_bounds__(256) void k_scan_write(const int* __restrict__ cnt,
                                                    const int* __restrict__ blkoff,
                                                    int* __restrict__ row_ptr, int N) {
    __shared__ int sc[256];
    int t = threadIdx.x;
    int base = blockIdx.x * 1024 + t * 4;
    int c[4];
    int s = 0;
    #pragma unroll
    for (int u = 0; u < 4; ++u) {
        int i = base + u;
        c[u] = (i < N) ? cnt[i] : 0;
        s += c[u];
    }
    sc[t] = s;
    __syncthreads();
    for (int o = 1; o < 256; o <<= 1) {
        int w = (t >= o) ? sc[t - o] : 0;
        __syncthreads();
        sc[t] += w;
        __syncthreads();
    }
    int run = blkoff[blockIdx.x] + (t ? sc[t - 1] : 0);
    #pragma unroll
    for (int u = 0; u < 4; ++u) {
        int i = base + u;
        if (i < N) { row_ptr[i] = run; run += c[u]; }
    }
}

__global__ __launch_bounds__(256) void k_fill(const int* __restrict__ ei, int E,
                                              const int* __restrict__ row_ptr,
                                              const float* __restrict__ dinv,
                                              int* __restrict__ fill,
                                              int2* __restrict__ packed) {
    int stride = gridDim.x * blockDim.x;
    for (int e = blockIdx.x * blockDim.x + threadIdx.x; e < E; e += stride) {
        int s = ei[e];
        int d = ei[E + e];
        int pos = atomicAdd(&fill[d], 1);
        packed[row_ptr[d] + pos] = make_int2(s, __float_as_int(dinv[s]));
    }
}

// ---------------- weight convert: W1t[n][k], W2t[n][k] in bf16 ----------------

__global__ __launch_bounds__(256) void k_convert(const float* __restrict__ W1,
                                                 const float* __restrict__ W2,
                                                 unsigned short* __restrict__ W1t,
                                                 unsigned short* __restrict__ W2t) {
    int idx = blockIdx.x * 256 + threadIdx.x;
    if (idx < 65536) {                       // W1: [k=256][n=256] -> W1t[n][k]
        int k = idx >> 8, n = idx & 255;
        W1t[n * 256 + k] = f2bf(W1[idx]);
    }
    int i2 = idx - 65536;
    if (i2 >= 0 && i2 < 16384) {             // W2: [k=256][n=64] -> W2t[n][k]
        int k = i2 >> 6, n = i2 & 63;
        W2t[n * 256 + k] = f2bf(W2[i2]);
    }
}

// ---------------- MFMA MLP: h0 = relu(x@W1+b1)@W2+b2 (bf16 in, fp32 acc) -----

__global__ __launch_bounds__(256) void k_mlp(const float* __restrict__ x,
                                             const unsigned short* __restrict__ W1t,
                                             const float* __restrict__ b1,
                                             const unsigned short* __restrict__ W2t,
                                             const float* __restrict__ b2,
                                             unsigned short* __restrict__ h0b,
                                             unsigned short* __restrict__ hAb,
                                             int N) {
    __shared__ unsigned short xs[64 * 256];
    int t = threadIdx.x;
    int base = blockIdx.x * 64;
    int w  = t >> 6;          // wave 0..3
    int l  = t & 63;
    int lr = l & 15;          // row-in-tile (A) / col-in-tile (B,D)
    int lk = l >> 4;          // k-group 0..3

    // ---- stage x tile (64 x 256 fp32 -> bf16), swizzled ----
    #pragma unroll
    for (int pass = 0; pass < 16; ++pass) {
        int f = pass * 256 + t;            // float4 id 0..4095
        int r = f >> 6;
        int c4 = (f & 63) << 2;
        float4 v = make_float4(0.f, 0.f, 0.f, 0.f);
        int row = base + r;
        if (row < N) v = *(const float4*)(x + (size_t)row * 256 + c4);
        int e = (r * 256 + c4) ^ ((r & 7) << 3);
        ushort4 pk;
        pk.x = f2bf(v.x); pk.y = f2bf(v.y); pk.z = f2bf(v.z); pk.w = f2bf(v.w);
        *(ushort4*)&xs[e] = pk;
    }
    __syncthreads();

    // ---- phase 1 ----
    floatx4 acc[4][4];
    #pragma unroll
    for (int mt = 0; mt < 4; ++mt)
        #pragma unroll
        for (int nt = 0; nt < 4; ++nt)
            acc[mt][nt] = (floatx4){0.f, 0.f, 0.f, 0.f};

    #pragma unroll
    for (int kc = 0; kc < 8; ++kc) {
        short8 af[4], bf[4];
        #pragma unroll
        for (int mt = 0; mt < 4; ++mt) {
            int m = mt * 16 + lr;
            int e = (m * 256 + kc * 32 + lk * 8) ^ ((m & 7) << 3);
            af[mt] = *(const short8*)&xs[e];
        }
        #pragma unroll
        for (int nt = 0; nt < 4; ++nt) {
            int n = w * 64 + nt * 16 + lr;
            bf[nt] = *(const short8*)&W1t[n * 256 + kc * 32 + lk * 8];
        }
        #pragma unroll
        for (int mt = 0; mt < 4; ++mt)
            #pragma unroll
            for (int nt = 0; nt < 4; ++nt)
                acc[mt][nt] = __builtin_amdgcn_mfma_f32_16x16x32_bf16(
                    af[mt], bf[nt], acc[mt][nt], 0, 0, 0);
    }

    float b1v[4];
    #pragma unroll
    for (int nt = 0; nt < 4; ++nt) b1v[nt] = b1[w * 64 + nt * 16 + lr];

    __syncthreads();   // all x-tile reads done before overwrite
    #pragma unroll
    for (int mt = 0; mt < 4; ++mt)
        #pragma unroll
        for (int nt = 0; nt < 4; ++nt)
            #pragma unroll
            for (int r = 0; r < 4; ++r) {
                int m = mt * 16 + lk * 4 + r;           // D row map
                int n = w * 64 + nt * 16 + lr;          // D col map
                float hv = fmaxf(acc[mt][nt][r] + b1v[nt], 0.f);
                xs[(m * 256 + n) ^ ((m & 7) << 3)] = f2bf(hv);
            }
    __syncthreads();

    // ---- phase 2 ----
    floatx4 acc2[4];
    #pragma unroll
    for (int nt = 0; nt < 4; ++nt) acc2[nt] = (floatx4){0.f, 0.f, 0.f, 0.f};

    #pragma unroll
    for (int kc = 0; kc < 8; ++kc) {
        int m = w * 16 + lr;
        int e = (m * 256 + kc * 32 + lk * 8) ^ ((m & 7) << 3);
        short8 af = *(const short8*)&xs[e];
        #pragma unroll
        for (int nt = 0; nt < 4; ++nt) {
            int n = nt * 16 + lr;
            short8 bf_ = *(const short8*)&W2t[n * 256 + kc * 32 + lk * 8];
            acc2[nt] = __builtin_amdgcn_mfma_f32_16x16x32_bf16(
                af, bf_, acc2[nt], 0, 0, 0);
        }
    }

    float b2v[4];
    #pragma unroll
    for (int nt = 0; nt < 4; ++nt) b2v[nt] = b2[nt * 16 + lr];

    #pragma unroll
    for (int nt = 0; nt < 4; ++nt)
        #pragma unroll
        for (int r = 0; r < 4; ++r) {
            int rg = base + w * 16 + lk * 4 + r;
            if (rg < N) {
                int col = nt * 16 + lr;
                unsigned short bv = f2bf(acc2[nt][r] + b2v[nt]);
                h0b[(size_t)rg * 64 + col] = bv;
                hAb[(size_t)rg * 64 + col] = bv;
            }
        }
}

// ---------------- propagation (bf16 h, fp32 accum) ----------------
// One wave per row. Lane owns a column PAIR (cl = (lane&31)*2, ushort2 loads);
// half-waves process alternating edges (2 edges per wave-step). Halves hold
// disjoint edge partial sums, combined with one shfl_xor(32); self-loop and
// h0 terms added after the combine. Inactive descriptor lanes are (0,0) so
// the odd-degree tail contributes weight 0 against row 0 -- safe, no guards.

__global__ __launch_bounds__(256) void k_prop(const unsigned short* __restrict__ h_in,
                                              unsigned short* __restrict__ h_out,
                                              const unsigned short* __restrict__ h0,
                                              const int* __restrict__ row_ptr,
                                              const int2* __restrict__ packed,
                                              const float* __restrict__ dinv,
                                              int N, int last,
                                              float* __restrict__ out) {
    int wid = threadIdx.x >> 6;
    int lane = threadIdx.x & 63;
    int half = lane >> 5;          // 0 or 1: which edge of each pair
    int cl = (lane & 31) * 2;      // column pair base
    int row = blockIdx.x * 4 + wid;
    if (row >= N) return;

    float dv = dinv[row];
    int p = row_ptr[row];
    int deg = row_ptr[row + 1] - p;

    float a0 = 0.f, a1 = 0.f;      // edge-sum only (self/h0 added post-combine)

    for (int b = 0; b < deg; b += 64) {
        int m = min(64, deg - b);
        int2 d = make_int2(0, 0);
        if (lane < m) d = packed[p + b + lane];
        int j = 0;
        for (; j + 16 <= m; j += 16) {       // 8 pair-steps = 16 edges
            #pragma unroll
            for (int u = 0; u < 8; ++u) {
                int idx = j + 2 * u + half;  // <= j+15 <= m-1, safe
                int s = __shfl(d.x, idx);
                float wgt = __int_as_float(__shfl(d.y, idx));
                ushort2 hv = *(const ushort2*)&h_in[(size_t)s * 64 + cl];
                a0 += wgt * bf2f(hv.x);
                a1 += wgt * bf2f(hv.y);
            }
        }
        for (; j < m; j += 2) {
            int idx = j + half;              // may hit lane m when m odd -> (0,0)
            int s = __shfl(d.x, idx);
            float wgt = __int_as_float(__shfl(d.y, idx));
            ushort2 hv = *(const ushort2*)&h_in[(size_t)s * 64 + cl];
            a0 += wgt * bf2f(hv.x);
            a1 += wgt * bf2f(hv.y);
        }
    }

    // combine the two half-wave edge subsets
    a0 += __shfl_xor(a0, 32);
    a1 += __shfl_xor(a1, 32);

    ushort2 sv  = *(const ushort2*)&h_in[(size_t)row * 64 + cl];
    ushort2 h0v = *(const ushort2*)&h0[(size_t)row * 64 + cl];
    float v0 = (1.0f - ALPHA) * (dv * (a0 + dv * bf2f(sv.x))) + ALPHA * bf2f(h0v.x);
    float v1 = (1.0f - ALPHA) * (dv * (a1 + dv * bf2f(sv.y))) + ALPHA * bf2f(h0v.y);

    if (!last) {
        if (half == 0) {
            ushort2 o;
            o.x = f2bf(v0); o.y = f2bf(v1);
            *(ushort2*)&h_out[(size_t)row * 64 + cl] = o;
        }
    } else {
        // each 32-lane half covers all 64 columns -> reduce within half
        float mx = fmaxf(v0, v1);
        #pragma unroll
        for (int o = 16; o; o >>= 1) mx = fmaxf(mx, __shfl_xor(mx, o));
        float es = __expf(v0 - mx) + __expf(v1 - mx);
        #pragma unroll
        for (int o = 16; o; o >>= 1) es += __shfl_xor(es, o);
        float lse = mx + logf(es);
        if (half == 0) {
            float2 o;
            o.x = v0 - lse; o.y = v1 - lse;
            *(float2*)&out[(size_t)row * 64 + cl] = o;
        }
    }
}

// ---------------- launch ----------------

extern "C" void kernel_launch(void* const* d_in, const int* in_sizes, int n_in,
                              void* d_out, int out_size, void* d_ws, size_t ws_size,
                              hipStream_t stream) {
    const float* x  = (const float*)d_in[0];
    const int*   ei = (const int*)d_in[1];
    const float* W1 = (const float*)d_in[2];
    const float* b1 = (const float*)d_in[3];
    const float* W2 = (const float*)d_in[4];
    const float* b2 = (const float*)d_in[5];
    float* out = (float*)d_out;

    int N = in_sizes[0] / 256;
    int E = in_sizes[1] / 2;
    int nblk = (N + 1023) / 1024;   // <= 128 for N <= 131072

    char* ws = (char*)d_ws;
    size_t off = 0;
    auto carve = [&](size_t bytes) -> void* {
        void* p = ws + off;
        off += (bytes + 255) & ~(size_t)255;
        return p;
    };
    int*            cnt     = (int*)carve((size_t)N * 4);
    int*            fillc   = (int*)carve((size_t)N * 4);
    int*            row_ptr = (int*)carve((size_t)(N + 1) * 4);
    int*            partial = (int*)carve((size_t)nblk * 4);
    int*            blkoff  = (int*)carve((size_t)nblk * 4);
    float*          dinv    = (float*)carve((size_t)N * 4);
    int2*           packed  = (int2*)carve((size_t)E * 8);
    unsigned short* W1t     = (unsigned short*)carve(256 * 256 * 2);
    unsigned short* W2t     = (unsigned short*)carve(64 * 256 * 2);
    unsigned short* h0b     = (unsigned short*)carve((size_t)N * 64 * 2);
    unsigned short* hAb     = (unsigned short*)carve((size_t)N * 64 * 2);
    unsigned short* hBb     = (unsigned short*)carve((size_t)N * 64 * 2);

    hipMemsetAsync(cnt, 0, (size_t)N * 4, stream);
    hipMemsetAsync(fillc, 0, (size_t)N * 4, stream);

    k_count<<<2048, 256, 0, stream>>>(ei, E, cnt);
    k_dinv<<<(N + 255) / 256, 256, 0, stream>>>(cnt, dinv, N);
    k_scan_part<<<nblk, 256, 0, stream>>>(cnt, partial, N);
    k_scan_off<<<1, 128, 0, stream>>>(partial, blkoff, row_ptr + N, nblk);
    k_scan_write<<<nblk, 256, 0, stream>>>(cnt, blkoff, row_ptr, N);
    k_fill<<<2048, 256, 0, stream>>>(ei, E, row_ptr, dinv, fillc, packed);
    k_convert<<<320, 256, 0, stream>>>(W1, W2, W1t, W2t);

    k_mlp<<<(N + 63) / 64, 256, 0, stream>>>(x, W1t, b1, W2t, b2, h0b, hAb, N);

    const unsigned short* hin = hAb;
    unsigned short* hout = hBb;
    for (int it = 0; it < K_ITERS; ++it) {
        int last = (it == K_ITERS - 1) ? 1 : 0;
        k_prop<<<(N + 3) / 4, 256, 0, stream>>>(hin, hout, h0b, row_ptr, packed,
                                                dinv, N, last, out);
        const unsigned short* tmp = hin;
        hin = hout;
        hout = (unsigned short*)tmp;
    }
}